// Round 8
// baseline (1246.284 us; speedup 1.0000x reference)
//
#include <hip/hip_runtime.h>

typedef __bf16 bf16_t;
typedef __bf16 bf16x8 __attribute__((ext_vector_type(8)));
typedef __bf16 bf16x4 __attribute__((ext_vector_type(4)));
typedef float  f32x4  __attribute__((ext_vector_type(4)));

#define NB 16   // B
#define NN 30   // N
#define NT 50   // T
#define ND 4    // D
#define NK 4    // K experts
#define NE 870  // E = N*(N-1)

// canonical workspace layout (element offsets from ws+16, all %8==0 -> 16B aligned)
#define C_INPUTS   0        // 96000
#define C_RELTYPE  96000    // 55680
#define C_B1       151680   // 512
#define C_B2       152192   // 512
#define C_OB1      152704   // 128
#define C_OB2      152832   // 128
#define C_OW3      152960   // 512
#define C_OB3      153472   // 4 (pad to 8)
#define C_W1F      153480   // 16384  W1 fragments  [k][ct][quad][lm][j] (quad>0 zero)
#define C_W2F      169864   // 65536  W2 fragments  [k][kc][quad][ct][lm][j]
#define C_OW1F     235400   // 20480  oW1 fragments [ct][kc(5)][quad][lm][j] (kk>=132 zero)
#define C_OW2F     255880   // 16384  oW2 fragments [ct][kc(4)][quad][lm][j]
#define AGG_BYTE_OFF (1u << 20)   // aggbuf (fp32) at ws + 1MB

__device__ __forceinline__ bf16x8 bzero8() {
  bf16x8 z;
#pragma unroll
  for (int j = 0; j < 8; ++j) z[j] = (bf16_t)0.0f;
  return z;
}

__device__ __forceinline__ f32x4 make4(float a, float b, float c, float d) {
  f32x4 v; v[0] = a; v[1] = b; v[2] = c; v[3] = d; return v;
}

// relu + cvt to bf16 + packed 8B store (vector-typed: alias-safe)
__device__ __forceinline__ void pack_store4(bf16_t* dst, f32x4 a) {
  bf16x4 v;
  v[0] = (bf16_t)fmaxf(a[0], 0.0f);
  v[1] = (bf16_t)fmaxf(a[1], 0.0f);
  v[2] = (bf16_t)fmaxf(a[2], 0.0f);
  v[3] = (bf16_t)fmaxf(a[3], 0.0f);
  *(bf16x4*)dst = v;
}

// ---------------------------------------------------------------------------
// dtype detection + canonicalization (bf16) + weight fragment pre-permutation
// ---------------------------------------------------------------------------
__device__ __forceinline__ int detect_isbf16(const void* p) {
  const unsigned short* w = (const unsigned short*)p;
  int c = 0;
#pragma unroll 4
  for (int i = 0; i < 256; i += 2) {
    const int e = (w[i] >> 7) & 0xFF;
    if (e >= 100 && e <= 150) ++c;
  }
  return c >= 96;   // bf16 ~128/128, fp32 ~25/128
}

__device__ __forceinline__ float ldf(const void* src, int idx, int isbf) {
  return isbf ? (float)((const bf16_t*)src)[idx] : ((const float*)src)[idx];
}

__device__ __forceinline__ void conv_arr(const void* src, bf16_t* dst, int n,
                                         int isbf, int gtid, int gsz) {
  if (isbf) {
    const unsigned short* s = (const unsigned short*)src;
    unsigned short* d = (unsigned short*)dst;
    for (int i = gtid; i < n; i += gsz) d[i] = s[i];
  } else {
    const float* s = (const float*)src;
    for (int i = gtid; i < n; i += gsz) dst[i] = (bf16_t)s[i];
  }
}

__global__ void convert_kernel(const void* inputs, const void* rel_type,
                               const void* W1, const void* b1,
                               const void* W2, const void* b2,
                               const void* oW1, const void* ob1,
                               const void* oW2, const void* ob2,
                               const void* oW3, const void* ob3,
                               void* ws)
{
  __shared__ int sflag;
  if (threadIdx.x == 0) sflag = detect_isbf16(inputs);
  __syncthreads();
  const int isbf = sflag;
  if (blockIdx.x == 0 && threadIdx.x == 0) *(int*)ws = isbf;
  bf16_t* cb = (bf16_t*)((char*)ws + 16);
  const int gtid = blockIdx.x * blockDim.x + threadIdx.x;
  const int gsz  = gridDim.x * blockDim.x;

  conv_arr(inputs,   cb + C_INPUTS,  96000, isbf, gtid, gsz);
  conv_arr(rel_type, cb + C_RELTYPE, 55680, isbf, gtid, gsz);
  conv_arr(b1,  cb + C_B1,  512, isbf, gtid, gsz);
  conv_arr(b2,  cb + C_B2,  512, isbf, gtid, gsz);
  conv_arr(ob1, cb + C_OB1, 128, isbf, gtid, gsz);
  conv_arr(ob2, cb + C_OB2, 128, isbf, gtid, gsz);
  conv_arr(oW3, cb + C_OW3, 512, isbf, gtid, gsz);
  conv_arr(ob3, cb + C_OB3, 4,   isbf, gtid, gsz);

  // W1 fragments: idx = (((k*8+ct)*4+quad)*16+lm)*8+j ; quad>0 -> 0
  for (int i = gtid; i < 16384; i += gsz) {
    const int j = i & 7, lm = (i >> 3) & 15, quad = (i >> 7) & 3;
    const int ct = (i >> 9) & 7, k = (i >> 12) & 3;
    float v = 0.0f;
    if (quad == 0) v = ldf(W1, k * 1024 + j * 128 + ct * 16 + lm, isbf);
    cb[C_W1F + i] = (bf16_t)v;
  }
  // W2 fragments: idx = ((((k*4+kc)*4+quad)*8)+ct)*128 + lm*8 + j
  for (int i = gtid; i < 65536; i += gsz) {
    const int j = i & 7, lm = (i >> 3) & 15, ct = (i >> 7) & 7;
    const int quad = (i >> 10) & 3, kc = (i >> 12) & 3, k = (i >> 14) & 3;
    const int kk = kc * 32 + quad * 8 + j;
    cb[C_W2F + i] = (bf16_t)ldf(W2, k * 16384 + kk * 128 + ct * 16 + lm, isbf);
  }
  // oW1 fragments: idx = (((ct*5+kc)*4+quad)*16+lm)*8+j ; kk>=132 -> 0
  for (int i = gtid; i < 20480; i += gsz) {
    const int j = i & 7, lm = (i >> 3) & 15, quad = (i >> 7) & 3;
    const int rem = i >> 9;              // 0..39
    const int kc = rem % 5, ct = rem / 5;
    const int kk = kc * 32 + quad * 8 + j;
    float v = 0.0f;
    if (kk < 132) v = ldf(oW1, kk * 128 + ct * 16 + lm, isbf);
    cb[C_OW1F + i] = (bf16_t)v;
  }
  // oW2 fragments: idx = (((ct*4+kc)*4+quad)*16+lm)*8+j
  for (int i = gtid; i < 16384; i += gsz) {
    const int j = i & 7, lm = (i >> 3) & 15, quad = (i >> 7) & 3;
    const int kc = (i >> 9) & 3, ct = (i >> 11) & 7;
    const int kk = kc * 32 + quad * 8 + j;
    cb[C_OW2F + i] = (bf16_t)ldf(oW2, kk * 128 + ct * 16 + lm, isbf);
  }
}

// ---------------------------------------------------------------------------
// Edge kernel. Per (b,t,half) block: 15 receiver nodes (435 edges), 4 experts.
// Pre-permuted W1/W2 fragment slices are staged per-k into LDS with a straight
// contiguous bf16x8 copy (no transpose -> no R3 conflict storm), and read AT
// USE via ds_read_b128 (m97 pattern). Live set ~70 regs by construction:
// R4/R6/R7's global-sourced register hoist spilled to scratch (178-259 MB
// writes, all pipes idle); LDS-sourced values are cheaply rematerializable so
// the RA does not spill them (R3 evidence: 22.7 MB writes, same VGPR count).
// ---------------------------------------------------------------------------
struct EdgeSmem {
  bf16_t h[64 * 136];      // 17408 B  layer-1 activations (wave-private rows)
  bf16_t w2lds[16384];     // 32768 B  W2F slice for current k
  bf16_t w1lds[4096];      // 8192 B   W1F slice for current k
  float  agg[16 * 128];    // 8192 B   (row 15 = scratch for the 1-node tile)
  float  rt4[436 * 4];     // 6976 B   rel_type slice, [edge_local][k]
  float  b1f4[512];        // 2048 B
  float  b2f4[512];        // 2048 B
  bf16_t xl[128];          // 256 B    x[b,t,:,:] (30 nodes x 4)
};                          // ~77.9 KB -> 2 blocks/CU

__global__ __launch_bounds__(256)
void edge_kernel(const bf16_t* __restrict__ inputs,
                 const bf16_t* __restrict__ rel_type,
                 const bf16_t* __restrict__ w1f_g,
                 const bf16_t* __restrict__ w2f_g,
                 const bf16_t* __restrict__ b1,
                 const bf16_t* __restrict__ b2,
                 float* __restrict__ aggbuf)
{
  __shared__ EdgeSmem s;
  const int tid  = threadIdx.x;
  const int bid  = blockIdx.x;
  const int nhalf = bid & 1;
  const int bt   = bid >> 1;
  const int b    = bt / NT;
  const int t    = bt - b * NT;
  const int wave = tid >> 6;
  const int lane = tid & 63;
  const int quad = lane >> 4;
  const int lm   = lane & 15;
  const int rowm = wave * 16 + lm;

  // ---- one-time staging ----
  if (tid < 30) {
    *(uint2*)&s.xl[tid * 4] = *(const uint2*)&inputs[((b * NN + tid) * NT + t) * ND];
  }
  for (int i = tid; i < 512; i += 256) {
    s.b1f4[i] = (float)b1[i];
    s.b2f4[i] = (float)b2[i];
  }
  {
    const int e0g = b * NE + nhalf * 435;
    for (int i = tid; i < 435; i += 256) {
      union { uint2 u2; bf16_t hh[4]; } c;
      c.u2 = *(const uint2*)&rel_type[(e0g + i) * NK];
#pragma unroll
      for (int kk = 0; kk < 4; ++kk) s.rt4[i * 4 + kk] = (float)c.hh[kk];
    }
  }
  for (int i = tid; i < 16 * 128; i += 256) s.agg[i] = 0.0f;

#pragma unroll 1
  for (int k = 0; k < NK; ++k) {
    __syncthreads();   // prior tiles done with w2lds/w1lds (k=0: initial staging)
    // ---- stage pre-permuted fragment slices: straight contiguous copy ----
    for (int i = tid; i < 2048; i += 256)
      *(bf16x8*)&s.w2lds[i * 8] = *(const bf16x8*)&w2f_g[k * 16384 + i * 8];
    for (int i = tid; i < 512; i += 256)
      *(bf16x8*)&s.w1lds[i * 8] = *(const bf16x8*)&w1f_g[k * 4096 + i * 8];
    __syncthreads();

    // small per-k bias hoist (40 regs)
    f32x4 b1v[8];
    float b2s[8];
#pragma unroll
    for (int ct = 0; ct < 8; ++ct) {
      const int nb = ct * 16 + quad * 4;
      b1v[ct] = make4(s.b1f4[k * 128 + nb],     s.b1f4[k * 128 + nb + 1],
                      s.b1f4[k * 128 + nb + 2], s.b1f4[k * 128 + nb + 3]);
      b2s[ct] = s.b2f4[k * 128 + ct * 16 + lm];
    }

#pragma unroll 1
    for (int tt = 0; tt < 8; ++tt) {
      const int vcnt = (tt < 7) ? 58 : 29;
      const int n0g  = nhalf * 15 + tt * 2;

      float rtv[4];
      bool  seg1[4];
#pragma unroll
      for (int r = 0; r < 4; ++r) {
        const int rr = wave * 16 + quad * 4 + r;
        rtv[r]  = (rr < vcnt) ? s.rt4[(tt * 58 + rr) * 4 + k] : 0.0f;
        seg1[r] = (rr >= 29);
      }

      // premsg B-fragment: [x_recv(4), x_send(4)] at k=0..7, zero elsewhere
      bf16x8 pm = bzero8();
      if (quad == 0 && rowm < vcnt) {
        const int recv = n0g + (rowm >= 29);
        const int jj   = rowm - ((rowm >= 29) ? 29 : 0);
        const int send = jj + ((jj >= recv) ? 1 : 0);
        union { uint2 u2[2]; bf16x8 v; } c;
        c.u2[0] = *(const uint2*)&s.xl[recv * 4];
        c.u2[1] = *(const uint2*)&s.xl[send * 4];
        pm = c.v;
      }

      // layer 1 (operand-swapped): W1 fragment read at use from LDS
#pragma unroll
      for (int ct = 0; ct < 8; ++ct) {
        const bf16x8 w1f = *(const bf16x8*)&s.w1lds[((ct * 4 + quad) * 16 + lm) * 8];
        f32x4 a1 = __builtin_amdgcn_mfma_f32_16x16x32_bf16(w1f, pm, b1v[ct], 0, 0, 0);
        pack_store4(&s.h[rowm * 136 + ct * 16 + quad * 4], a1);
      }

      // layer 2 (un-swapped): W2 fragments read at use from LDS
      f32x4 acc2[8];
#pragma unroll
      for (int ct = 0; ct < 8; ++ct)
        acc2[ct] = make4(b2s[ct], b2s[ct], b2s[ct], b2s[ct]);
#pragma unroll
      for (int kc = 0; kc < 4; ++kc) {
        const bf16x8 af = *(const bf16x8*)&s.h[rowm * 136 + kc * 32 + quad * 8];
#pragma unroll
        for (int ct = 0; ct < 8; ++ct) {
          const bf16x8 w2f = *(const bf16x8*)&s.w2lds[(((kc * 4 + quad) * 8) + ct) * 128 + lm * 8];
          acc2[ct] = __builtin_amdgcn_mfma_f32_16x16x32_bf16(af, w2f, acc2[ct], 0, 0, 0);
        }
      }

      // relu * rt, segmented reduce over 16 edges (4 regs + quad butterfly)
#pragma unroll
      for (int ct = 0; ct < 8; ++ct) {
        float p0 = 0.0f, p1 = 0.0f;
#pragma unroll
        for (int r = 0; r < 4; ++r) {
          const float v = fmaxf(acc2[ct][r], 0.0f) * rtv[r];
          p0 += seg1[r] ? 0.0f : v;
          p1 += seg1[r] ? v : 0.0f;
        }
        p0 += __shfl_xor(p0, 16, 64);
        p0 += __shfl_xor(p0, 32, 64);
        p1 += __shfl_xor(p1, 16, 64);
        p1 += __shfl_xor(p1, 32, 64);
        if (quad == 0) {
          const int col = ct * 16 + lm;
          atomicAdd(&s.agg[(tt * 2) * 128 + col], p0);
          atomicAdd(&s.agg[(tt * 2 + 1) * 128 + col], p1);
        }
      }
    }
  }

  __syncthreads();
  for (int i = tid; i < 15 * 128; i += 256) {
    const int r = i >> 7, c = i & 127;
    aggbuf[(size_t)(bt * NN + nhalf * 15 + r) * 128 + c] = s.agg[r * 128 + c];
  }
}

// ---------------------------------------------------------------------------
// Node kernel: 64 node-instances per block; weights loaded at use (L2-hot),
// ~60 live regs, wave-private h1/h2, single initial barrier (round-4 logic).
// ---------------------------------------------------------------------------
struct NodeSmem {
  bf16_t h1[64 * 136];     // 17408 B
  bf16_t h2[64 * 136];     // 17408 B
  bf16_t xres[64 * 4];
  float  b1f[128];
  float  b2f[128];
  float  w3f[128 * 4];
  float  b3f[4];
};                          // ~38.4 KB

__global__ __launch_bounds__(256)
void node_kernel(const bf16_t* __restrict__ inputs,
                 const bf16_t* __restrict__ ow1f_g, const bf16_t* __restrict__ ob1,
                 const bf16_t* __restrict__ ow2f_g, const bf16_t* __restrict__ ob2,
                 const bf16_t* __restrict__ oW3, const bf16_t* __restrict__ ob3,
                 const int* __restrict__ flagptr,
                 const float* __restrict__ aggbuf,
                 void* __restrict__ outp)
{
  __shared__ NodeSmem s;
  const int tid  = threadIdx.x;
  const int wave = tid >> 6;
  const int lane = tid & 63;
  const int quad = lane >> 4;
  const int lm   = lane & 15;
  const int row  = wave * 16 + lm;
  const int r0   = blockIdx.x * 64;
  const int isbf = *flagptr;

  // ---- one-time staging (single barrier) ----
  if (tid < 64) {
    const int r  = r0 + tid;
    const int n  = r % NN;
    const int bt = r / NN;
    const int t  = bt % NT;
    const int b  = bt / NT;
    *(uint2*)&s.xres[tid * 4] = *(const uint2*)&inputs[((b * NN + n) * NT + t) * ND];
  }
  if (tid < 128) s.b1f[tid] = (float)ob1[tid];
  else           s.b2f[tid - 128] = (float)ob2[tid - 128];
  if (tid < 4) s.b3f[tid] = (float)ob3[tid];
  for (int i = tid; i < 512; i += 256) s.w3f[i] = (float)oW3[i];
  __syncthreads();

  // ---- build aug B-fragments directly from global agg (fp32) + x ----
  bf16x8 bfa[5];
  {
    const float* aggrow = aggbuf + (size_t)(r0 + row) * 128;
    float tmp[8];
    if (quad == 0) {
#pragma unroll
      for (int j = 0; j < 4; ++j) tmp[j] = (float)s.xres[row * 4 + j];
      const float4 a = *(const float4*)(aggrow);
      tmp[4] = a.x; tmp[5] = a.y; tmp[6] = a.z; tmp[7] = a.w;
    } else {
      const int c0 = quad * 8 - 4;
      const float4 a = *(const float4*)(aggrow + c0);
      const float4 d = *(const float4*)(aggrow + c0 + 4);
      tmp[0] = a.x; tmp[1] = a.y; tmp[2] = a.z; tmp[3] = a.w;
      tmp[4] = d.x; tmp[5] = d.y; tmp[6] = d.z; tmp[7] = d.w;
    }
#pragma unroll
    for (int j = 0; j < 8; ++j) bfa[0][j] = (bf16_t)tmp[j];
#pragma unroll
    for (int kc = 1; kc < 4; ++kc) {
      const int c0 = kc * 32 + quad * 8 - 4;
      const float4 a = *(const float4*)(aggrow + c0);
      const float4 d = *(const float4*)(aggrow + c0 + 4);
      tmp[0] = a.x; tmp[1] = a.y; tmp[2] = a.z; tmp[3] = a.w;
      tmp[4] = d.x; tmp[5] = d.y; tmp[6] = d.z; tmp[7] = d.w;
#pragma unroll
      for (int j = 0; j < 8; ++j) bfa[kc][j] = (bf16_t)tmp[j];
    }
    if (quad == 0) {
      const float4 a = *(const float4*)(aggrow + 124);
      tmp[0] = a.x; tmp[1] = a.y; tmp[2] = a.z; tmp[3] = a.w;
      tmp[4] = 0.f; tmp[5] = 0.f; tmp[6] = 0.f; tmp[7] = 0.f;
#pragma unroll
      for (int j = 0; j < 8; ++j) bfa[4][j] = (bf16_t)tmp[j];
    } else bfa[4] = bzero8();
  }

  // ---- layer 1 (swapped), weights at use: h1[row][n] ----
#pragma unroll
  for (int ct = 0; ct < 8; ++ct) {
    const int nb = ct * 16 + quad * 4;
    f32x4 acc = make4(s.b1f[nb], s.b1f[nb + 1], s.b1f[nb + 2], s.b1f[nb + 3]);
#pragma unroll
    for (int kc = 0; kc < 5; ++kc) {
      const bf16x8 w = *(const bf16x8*)&ow1f_g[(((ct * 5 + kc) * 4 + quad) * 16 + lm) * 8];
      acc = __builtin_amdgcn_mfma_f32_16x16x32_bf16(w, bfa[kc], acc, 0, 0, 0);
    }
    pack_store4(&s.h1[row * 136 + ct * 16 + quad * 4], acc);
  }
  // no barrier: h1 rows are wave-private

  bf16x8 af[4];
#pragma unroll
  for (int kc = 0; kc < 4; ++kc)
    af[kc] = *(const bf16x8*)&s.h1[row * 136 + kc * 32 + quad * 8];

  // ---- layer 2 (swapped), weights at use: h2[row][m] ----
#pragma unroll
  for (int ct = 0; ct < 8; ++ct) {
    const int mb = ct * 16 + quad * 4;
    f32x4 acc = make4(s.b2f[mb], s.b2f[mb + 1], s.b2f[mb + 2], s.b2f[mb + 3]);
#pragma unroll
    for (int kc = 0; kc < 4; ++kc) {
      const bf16x8 w = *(const bf16x8*)&ow2f_g[(((ct * 4 + kc) * 4 + quad) * 16 + lm) * 8];
      acc = __builtin_amdgcn_mfma_f32_16x16x32_bf16(w, af[kc], acc, 0, 0, 0);
    }
    pack_store4(&s.h2[row * 136 + ct * 16 + quad * 4], acc);
  }
  // no barrier: layer-3 lanes read their own wave's rows

  // ---- layer 3 (VALU) + residual + store ----
  {
    const int rloc = tid >> 2;
    const int d    = tid & 3;
    float a3 = s.b3f[d];
#pragma unroll
    for (int g = 0; g < 16; ++g) {
      const bf16x8 hv = *(const bf16x8*)&s.h2[rloc * 136 + g * 8];
#pragma unroll
      for (int j = 0; j < 8; ++j)
        a3 += (float)hv[j] * s.w3f[(g * 8 + j) * 4 + d];
    }
    a3 += (float)s.xres[rloc * 4 + d];
    const int r  = r0 + rloc;
    const int n  = r % NN;
    const int bt = r / NN;
    const int t  = bt % NT;
    const int b  = bt / NT;
    if (t < NT - 1) {
      const int oidx = ((b * NN + n) * (NT - 1) + t) * ND + d;
      if (isbf) ((bf16_t*)outp)[oidx] = (bf16_t)a3;
      else      ((float*)outp)[oidx]  = a3;
    }
  }
}

extern "C" void kernel_launch(void* const* d_in, const int* in_sizes, int n_in,
                              void* d_out, int out_size, void* d_ws, size_t ws_size,
                              hipStream_t stream) {
  // d_in[2] rel_rec, d_in[3] rel_send: fixed one-hot structure, computed
  // analytically. d_in[14] pred_steps == 1.
  char* ws = (char*)d_ws;
  bf16_t* cb = (bf16_t*)(ws + 16);             // canonical bf16 arrays + fragments
  float* aggbuf = (float*)(ws + AGG_BYTE_OFF); // 24000*128*4 B = 12.29 MB

  convert_kernel<<<dim3(256), dim3(256), 0, stream>>>(
      d_in[0], d_in[1], d_in[4], d_in[5], d_in[6], d_in[7],
      d_in[8], d_in[9], d_in[10], d_in[11], d_in[12], d_in[13], d_ws);

  edge_kernel<<<dim3(NB * NT * 2), dim3(256), 0, stream>>>(
      cb + C_INPUTS, cb + C_RELTYPE, cb + C_W1F, cb + C_W2F,
      cb + C_B1, cb + C_B2, aggbuf);

  node_kernel<<<dim3((NB * NT * NN) / 64), dim3(256), 0, stream>>>(
      cb + C_INPUTS, cb + C_OW1F, cb + C_OB1, cb + C_OW2F, cb + C_OB2,
      cb + C_OW3, cb + C_OB3, (const int*)d_ws, aggbuf, d_out);
}

// Round 9
// 669.059 us; speedup vs baseline: 1.8627x; 1.8627x over previous
//
#include <hip/hip_runtime.h>

typedef __bf16 bf16_t;
typedef __bf16 bf16x8 __attribute__((ext_vector_type(8)));
typedef __bf16 bf16x4 __attribute__((ext_vector_type(4)));
typedef float  f32x4  __attribute__((ext_vector_type(4)));

#define NB 16   // B
#define NN 30   // N
#define NT 50   // T
#define ND 4    // D
#define NK 4    // K experts
#define NE 870  // E = N*(N-1)

// canonical workspace layout (element offsets from ws+16, all %8==0 -> 16B aligned)
#define C_INPUTS   0        // 96000
#define C_RELTYPE  96000    // 55680
#define C_B2       152192   // 512
#define C_OB1      152704   // 128
#define C_OB2      152832   // 128
#define C_OW3      152960   // 512
#define C_OB3      153472   // 4 (pad to 8)
#define C_W1F      153480   // 16384  W1 frags [k][ct][quad][lm][j]; b1 folded at quad1,j0
#define C_W2F      169864   // 65536  W2 frags [k][kc][ct][quad*16+lm][j]  (contiguous/frag)
#define C_OW1F     235400   // 20480  oW1 frags [ct][kc(5)][quad][lm][j] (kk>=132 zero)
#define C_OW2F     255880   // 16384  oW2 frags [ct][kc(4)][quad][lm][j]
#define AGG_BYTE_OFF (1u << 20)   // aggbuf (fp32) at ws + 1MB

__device__ __forceinline__ bf16x8 bzero8() {
  bf16x8 z;
#pragma unroll
  for (int j = 0; j < 8; ++j) z[j] = (bf16_t)0.0f;
  return z;
}

__device__ __forceinline__ f32x4 make4(float a, float b, float c, float d) {
  f32x4 v; v[0] = a; v[1] = b; v[2] = c; v[3] = d; return v;
}

// relu + cvt to bf16 + packed 8B store (vector-typed: alias-safe)
__device__ __forceinline__ void pack_store4(bf16_t* dst, f32x4 a) {
  bf16x4 v;
  v[0] = (bf16_t)fmaxf(a[0], 0.0f);
  v[1] = (bf16_t)fmaxf(a[1], 0.0f);
  v[2] = (bf16_t)fmaxf(a[2], 0.0f);
  v[3] = (bf16_t)fmaxf(a[3], 0.0f);
  *(bf16x4*)dst = v;
}

// ---------------------------------------------------------------------------
// dtype detection + canonicalization (bf16) + weight fragment pre-permutation
// ---------------------------------------------------------------------------
__device__ __forceinline__ int detect_isbf16(const void* p) {
  const unsigned short* w = (const unsigned short*)p;
  int c = 0;
#pragma unroll 4
  for (int i = 0; i < 256; i += 2) {
    const int e = (w[i] >> 7) & 0xFF;
    if (e >= 100 && e <= 150) ++c;
  }
  return c >= 96;   // bf16 ~128/128, fp32 ~25/128
}

__device__ __forceinline__ float ldf(const void* src, int idx, int isbf) {
  return isbf ? (float)((const bf16_t*)src)[idx] : ((const float*)src)[idx];
}

__device__ __forceinline__ void conv_arr(const void* src, bf16_t* dst, int n,
                                         int isbf, int gtid, int gsz) {
  if (isbf) {
    const unsigned short* s = (const unsigned short*)src;
    unsigned short* d = (unsigned short*)dst;
    for (int i = gtid; i < n; i += gsz) d[i] = s[i];
  } else {
    const float* s = (const float*)src;
    for (int i = gtid; i < n; i += gsz) dst[i] = (bf16_t)s[i];
  }
}

__global__ void convert_kernel(const void* inputs, const void* rel_type,
                               const void* W1, const void* b1,
                               const void* W2, const void* b2,
                               const void* oW1, const void* ob1,
                               const void* oW2, const void* ob2,
                               const void* oW3, const void* ob3,
                               void* ws)
{
  __shared__ int sflag;
  if (threadIdx.x == 0) sflag = detect_isbf16(inputs);
  __syncthreads();
  const int isbf = sflag;
  if (blockIdx.x == 0 && threadIdx.x == 0) *(int*)ws = isbf;
  bf16_t* cb = (bf16_t*)((char*)ws + 16);
  const int gtid = blockIdx.x * blockDim.x + threadIdx.x;
  const int gsz  = gridDim.x * blockDim.x;

  conv_arr(inputs,   cb + C_INPUTS,  96000, isbf, gtid, gsz);
  conv_arr(rel_type, cb + C_RELTYPE, 55680, isbf, gtid, gsz);
  conv_arr(b2,  cb + C_B2,  512, isbf, gtid, gsz);
  conv_arr(ob1, cb + C_OB1, 128, isbf, gtid, gsz);
  conv_arr(ob2, cb + C_OB2, 128, isbf, gtid, gsz);
  conv_arr(oW3, cb + C_OW3, 512, isbf, gtid, gsz);
  conv_arr(ob3, cb + C_OB3, 4,   isbf, gtid, gsz);

  // W1 fragments: idx = (((k*8+ct)*4+quad)*16+lm)*8+j
  // quad==0: W1[k][kk=j][n]; quad==1 && j==0: b1[k][n] (bias feature kk=8); else 0
  for (int i = gtid; i < 16384; i += gsz) {
    const int j = i & 7, lm = (i >> 3) & 15, quad = (i >> 7) & 3;
    const int ct = (i >> 9) & 7, k = (i >> 12) & 3;
    float v = 0.0f;
    if (quad == 0)                 v = ldf(W1, k * 1024 + j * 128 + ct * 16 + lm, isbf);
    else if (quad == 1 && j == 0)  v = ldf(b1, k * 128 + ct * 16 + lm, isbf);
    cb[C_W1F + i] = (bf16_t)v;
  }
  // W2 fragments, per-(kc,ct) contiguous: idx = (((k*4+kc)*8+ct)*64 + quad*16+lm)*8 + j
  for (int i = gtid; i < 65536; i += gsz) {
    const int j = i & 7;
    const int l64 = (i >> 3) & 63;          // quad*16+lm
    const int ct = (i >> 9) & 7, kc = (i >> 12) & 3, k = (i >> 14) & 3;
    const int quad = l64 >> 4, lm = l64 & 15;
    const int kk = kc * 32 + quad * 8 + j;
    cb[C_W2F + i] = (bf16_t)ldf(W2, k * 16384 + kk * 128 + ct * 16 + lm, isbf);
  }
  // oW1 fragments: idx = (((ct*5+kc)*4+quad)*16+lm)*8+j ; kk>=132 -> 0
  for (int i = gtid; i < 20480; i += gsz) {
    const int j = i & 7, lm = (i >> 3) & 15, quad = (i >> 7) & 3;
    const int rem = i >> 9;              // 0..39
    const int kc = rem % 5, ct = rem / 5;
    const int kk = kc * 32 + quad * 8 + j;
    float v = 0.0f;
    if (kk < 132) v = ldf(oW1, kk * 128 + ct * 16 + lm, isbf);
    cb[C_OW1F + i] = (bf16_t)v;
  }
  // oW2 fragments: idx = (((ct*4+kc)*4+quad)*16+lm)*8+j
  for (int i = gtid; i < 16384; i += gsz) {
    const int j = i & 7, lm = (i >> 3) & 15, quad = (i >> 7) & 3;
    const int kc = (i >> 9) & 3, ct = (i >> 11) & 7;
    const int kk = kc * 32 + quad * 8 + j;
    cb[C_OW2F + i] = (bf16_t)ldf(oW2, kk * 128 + ct * 16 + lm, isbf);
  }
}

// ---------------------------------------------------------------------------
// Edge kernel (R6-verified logic + R8's no-spill regime).
// Wave w owns output cols ct in [(w&1)*4, +4) and edge strips 2*(w>>1)..+1.
// W1/W2 fragments hoisted per-k from global (contiguous 1KB loads, L2-hot);
// plain __launch_bounds__(256) -> RA allocates ~132+ VGPRs, ~115 live fits
// (the min-waves arg in R4/R6 was what forced 128/64-reg allocs + spill).
// h lives in LDS in A-FRAGMENT order -> layer-2 reads are wave-contiguous
// ds_read_b128 (conflict-free); layer-1 C-layout output maps to one aligned
// b64 store per (strip,ct). Two barriers per tile.
// ---------------------------------------------------------------------------
struct EdgeSmem {
  bf16_t h[8192];          // 16384 B  h1 A-fragments [strip][kc][quad*16+lm][j]
  float  agg[16 * 128];    // 8192 B   (row 15 = scratch for the 1-node tile)
  float  rt4[436 * 4];     // 6976 B   rel_type slice, [edge_local][k]
  float  b2f4[512];        // 2048 B
  bf16_t xl[128];          // 256 B    x[b,t,:,:] (30 nodes x 4)
};                          // ~33.9 KB

__global__ __launch_bounds__(256)
void edge_kernel(const bf16_t* __restrict__ inputs,
                 const bf16_t* __restrict__ rel_type,
                 const bf16_t* __restrict__ w1f_g,
                 const bf16_t* __restrict__ w2f_g,
                 const bf16_t* __restrict__ b2,
                 float* __restrict__ aggbuf)
{
  __shared__ EdgeSmem s;
  const int tid  = threadIdx.x;
  const int bid  = blockIdx.x;
  const int nhalf = bid & 1;
  const int bt   = bid >> 1;
  const int b    = bt / NT;
  const int t    = bt - b * NT;
  const int wave = tid >> 6;
  const int lane = tid & 63;
  const int quad = lane >> 4;
  const int lm   = lane & 15;
  const int ctbase = (wave & 1) * 4;     // this wave's output-col half
  const int spair  = (wave >> 1) * 2;    // first strip of this wave's pair

  // ---- one-time staging ----
  if (tid < 30) {
    *(uint2*)&s.xl[tid * 4] = *(const uint2*)&inputs[((b * NN + tid) * NT + t) * ND];
  }
  for (int i = tid; i < 512; i += 256) s.b2f4[i] = (float)b2[i];
  {
    const int e0g = b * NE + nhalf * 435;
    for (int i = tid; i < 435; i += 256) {
      union { uint2 u2; bf16_t hh[4]; } c;
      c.u2 = *(const uint2*)&rel_type[(e0g + i) * NK];
#pragma unroll
      for (int kk = 0; kk < 4; ++kk) s.rt4[i * 4 + kk] = (float)c.hh[kk];
    }
  }
  for (int i = tid; i < 16 * 128; i += 256) s.agg[i] = 0.0f;
  __syncthreads();

#pragma unroll 1
  for (int k = 0; k < NK; ++k) {
    // ---- per-k hoist for MY ct-half: 80 regs, fully-contiguous L2 loads ----
    bf16x8 w1r[4];
    bf16x8 w2r[4][4];
    float  b2s[4];
#pragma unroll
    for (int c = 0; c < 4; ++c) {
      const int ct = ctbase + c;
      w1r[c] = *(const bf16x8*)&w1f_g[(((k * 8 + ct) * 4 + quad) * 16 + lm) * 8];
#pragma unroll
      for (int kc = 0; kc < 4; ++kc)
        w2r[c][kc] = *(const bf16x8*)&w2f_g[((((k * 4 + kc) * 8) + ct) * 64 + quad * 16 + lm) * 8];
      b2s[c] = s.b2f4[k * 128 + ct * 16 + lm];
    }

#pragma unroll 1
    for (int tt = 0; tt < 8; ++tt) {
      const int vcnt = (tt < 7) ? 58 : 29;
      const int n0g  = nhalf * 15 + tt * 2;

      // ---- layer 1: both strips of the pair, my 64 output cols ----
#pragma unroll
      for (int si = 0; si < 2; ++si) {
        const int strip = spair + si;
        const int rr = strip * 16 + lm;          // edge-in-tile (B col)
        bf16x8 pm = bzero8();
        if (quad == 0) {
          if (rr < vcnt) {
            const int recv = n0g + (rr >= 29);
            const int jj   = rr - ((rr >= 29) ? 29 : 0);
            const int send = jj + ((jj >= recv) ? 1 : 0);
            union { uint2 u2[2]; bf16x8 v; } c;
            c.u2[0] = *(const uint2*)&s.xl[recv * 4];
            c.u2[1] = *(const uint2*)&s.xl[send * 4];
            pm = c.v;
          }
        } else if (quad == 1) {
          pm[0] = (bf16_t)1.0f;   // bias feature (kk=8): W1F row holds b1
        }
        const f32x4 z4 = make4(0.0f, 0.0f, 0.0f, 0.0f);
#pragma unroll
        for (int c = 0; c < 4; ++c) {
          const int ct = ctbase + c;
          f32x4 a1 = __builtin_amdgcn_mfma_f32_16x16x32_bf16(w1r[c], pm, z4, 0, 0, 0);
          // C-layout (n=quad*4+r, edge=lm) -> A-fragment slot:
          //   kc = ct>>1, q' = 2*(ct&1)+(quad>>1), j = 4*(quad&1)+r
          const int qr = 2 * (ct & 1) + (quad >> 1);
          pack_store4(&s.h[((strip * 4 + (ct >> 1)) * 64 + qr * 16 + lm) * 8 + 4 * (quad & 1)], a1);
        }
      }
      __syncthreads();   // h fragments complete (written across wave pairs)

      // ---- layer 2 + fused epilogue ----
#pragma unroll
      for (int si = 0; si < 2; ++si) {
        const int strip = spair + si;
        bf16x8 af[4];
#pragma unroll
        for (int kc = 0; kc < 4; ++kc)
          af[kc] = *(const bf16x8*)&s.h[((strip * 4 + kc) * 64 + quad * 16 + lm) * 8];
        float rtv[4];
        bool  sg[4];
#pragma unroll
        for (int r = 0; r < 4; ++r) {
          const int rr2 = strip * 16 + quad * 4 + r;
          rtv[r] = (rr2 < vcnt) ? s.rt4[(tt * 58 + rr2) * 4 + k] : 0.0f;
          sg[r]  = rr2 >= 29;
        }
#pragma unroll
        for (int c = 0; c < 4; ++c) {
          f32x4 acc = make4(b2s[c], b2s[c], b2s[c], b2s[c]);
#pragma unroll
          for (int kc = 0; kc < 4; ++kc)
            acc = __builtin_amdgcn_mfma_f32_16x16x32_bf16(af[kc], w2r[c][kc], acc, 0, 0, 0);
          float p0 = 0.0f, p1 = 0.0f;
#pragma unroll
          for (int r = 0; r < 4; ++r) {
            const float v = fmaxf(acc[r], 0.0f) * rtv[r];
            p0 += sg[r] ? 0.0f : v;
            p1 += sg[r] ? v : 0.0f;
          }
          p0 += __shfl_xor(p0, 16, 64);
          p0 += __shfl_xor(p0, 32, 64);
          p1 += __shfl_xor(p1, 16, 64);
          p1 += __shfl_xor(p1, 32, 64);
          if (quad == 0) {
            const int col = (ctbase + c) * 16 + lm;
            atomicAdd(&s.agg[(tt * 2) * 128 + col], p0);
            atomicAdd(&s.agg[(tt * 2 + 1) * 128 + col], p1);
          }
        }
      }
      __syncthreads();   // h consumed; next tile may overwrite
    }
  }

  for (int i = tid; i < 15 * 128; i += 256) {
    const int r = i >> 7, c = i & 127;
    aggbuf[(size_t)(bt * NN + nhalf * 15 + r) * 128 + c] = s.agg[r * 128 + c];
  }
}

// ---------------------------------------------------------------------------
// Node kernel: 64 node-instances per block; weights loaded at use (L2-hot),
// ~60 live regs, wave-private h1/h2, single initial barrier (R8-verified).
// ---------------------------------------------------------------------------
struct NodeSmem {
  bf16_t h1[64 * 136];     // 17408 B
  bf16_t h2[64 * 136];     // 17408 B
  bf16_t xres[64 * 4];
  float  b1f[128];
  float  b2f[128];
  float  w3f[128 * 4];
  float  b3f[4];
};                          // ~38.4 KB

__global__ __launch_bounds__(256)
void node_kernel(const bf16_t* __restrict__ inputs,
                 const bf16_t* __restrict__ ow1f_g, const bf16_t* __restrict__ ob1,
                 const bf16_t* __restrict__ ow2f_g, const bf16_t* __restrict__ ob2,
                 const bf16_t* __restrict__ oW3, const bf16_t* __restrict__ ob3,
                 const int* __restrict__ flagptr,
                 const float* __restrict__ aggbuf,
                 void* __restrict__ outp)
{
  __shared__ NodeSmem s;
  const int tid  = threadIdx.x;
  const int wave = tid >> 6;
  const int lane = tid & 63;
  const int quad = lane >> 4;
  const int lm   = lane & 15;
  const int row  = wave * 16 + lm;
  const int r0   = blockIdx.x * 64;
  const int isbf = *flagptr;

  // ---- one-time staging (single barrier) ----
  if (tid < 64) {
    const int r  = r0 + tid;
    const int n  = r % NN;
    const int bt = r / NN;
    const int t  = bt % NT;
    const int b  = bt / NT;
    *(uint2*)&s.xres[tid * 4] = *(const uint2*)&inputs[((b * NN + n) * NT + t) * ND];
  }
  if (tid < 128) s.b1f[tid] = (float)ob1[tid];
  else           s.b2f[tid - 128] = (float)ob2[tid - 128];
  if (tid < 4) s.b3f[tid] = (float)ob3[tid];
  for (int i = tid; i < 512; i += 256) s.w3f[i] = (float)oW3[i];
  __syncthreads();

  // ---- build aug B-fragments directly from global agg (fp32) + x ----
  bf16x8 bfa[5];
  {
    const float* aggrow = aggbuf + (size_t)(r0 + row) * 128;
    float tmp[8];
    if (quad == 0) {
#pragma unroll
      for (int j = 0; j < 4; ++j) tmp[j] = (float)s.xres[row * 4 + j];
      const float4 a = *(const float4*)(aggrow);
      tmp[4] = a.x; tmp[5] = a.y; tmp[6] = a.z; tmp[7] = a.w;
    } else {
      const int c0 = quad * 8 - 4;
      const float4 a = *(const float4*)(aggrow + c0);
      const float4 d = *(const float4*)(aggrow + c0 + 4);
      tmp[0] = a.x; tmp[1] = a.y; tmp[2] = a.z; tmp[3] = a.w;
      tmp[4] = d.x; tmp[5] = d.y; tmp[6] = d.z; tmp[7] = d.w;
    }
#pragma unroll
    for (int j = 0; j < 8; ++j) bfa[0][j] = (bf16_t)tmp[j];
#pragma unroll
    for (int kc = 1; kc < 4; ++kc) {
      const int c0 = kc * 32 + quad * 8 - 4;
      const float4 a = *(const float4*)(aggrow + c0);
      const float4 d = *(const float4*)(aggrow + c0 + 4);
      tmp[0] = a.x; tmp[1] = a.y; tmp[2] = a.z; tmp[3] = a.w;
      tmp[4] = d.x; tmp[5] = d.y; tmp[6] = d.z; tmp[7] = d.w;
#pragma unroll
      for (int j = 0; j < 8; ++j) bfa[kc][j] = (bf16_t)tmp[j];
    }
    if (quad == 0) {
      const float4 a = *(const float4*)(aggrow + 124);
      tmp[0] = a.x; tmp[1] = a.y; tmp[2] = a.z; tmp[3] = a.w;
      tmp[4] = 0.f; tmp[5] = 0.f; tmp[6] = 0.f; tmp[7] = 0.f;
#pragma unroll
      for (int j = 0; j < 8; ++j) bfa[4][j] = (bf16_t)tmp[j];
    } else bfa[4] = bzero8();
  }

  // ---- layer 1 (swapped), weights at use: h1[row][n] ----
#pragma unroll
  for (int ct = 0; ct < 8; ++ct) {
    const int nb = ct * 16 + quad * 4;
    f32x4 acc = make4(s.b1f[nb], s.b1f[nb + 1], s.b1f[nb + 2], s.b1f[nb + 3]);
#pragma unroll
    for (int kc = 0; kc < 5; ++kc) {
      const bf16x8 w = *(const bf16x8*)&ow1f_g[(((ct * 5 + kc) * 4 + quad) * 16 + lm) * 8];
      acc = __builtin_amdgcn_mfma_f32_16x16x32_bf16(w, bfa[kc], acc, 0, 0, 0);
    }
    pack_store4(&s.h1[row * 136 + ct * 16 + quad * 4], acc);
  }
  // no barrier: h1 rows are wave-private

  bf16x8 af[4];
#pragma unroll
  for (int kc = 0; kc < 4; ++kc)
    af[kc] = *(const bf16x8*)&s.h1[row * 136 + kc * 32 + quad * 8];

  // ---- layer 2 (swapped), weights at use: h2[row][m] ----
#pragma unroll
  for (int ct = 0; ct < 8; ++ct) {
    const int mb = ct * 16 + quad * 4;
    f32x4 acc = make4(s.b2f[mb], s.b2f[mb + 1], s.b2f[mb + 2], s.b2f[mb + 3]);
#pragma unroll
    for (int kc = 0; kc < 4; ++kc) {
      const bf16x8 w = *(const bf16x8*)&ow2f_g[(((ct * 4 + kc) * 4 + quad) * 16 + lm) * 8];
      acc = __builtin_amdgcn_mfma_f32_16x16x32_bf16(w, af[kc], acc, 0, 0, 0);
    }
    pack_store4(&s.h2[row * 136 + ct * 16 + quad * 4], acc);
  }
  // no barrier: layer-3 lanes read their own wave's rows

  // ---- layer 3 (VALU) + residual + store ----
  {
    const int rloc = tid >> 2;
    const int d    = tid & 3;
    float a3 = s.b3f[d];
#pragma unroll
    for (int g = 0; g < 16; ++g) {
      const bf16x8 hv = *(const bf16x8*)&s.h2[rloc * 136 + g * 8];
#pragma unroll
      for (int j = 0; j < 8; ++j)
        a3 += (float)hv[j] * s.w3f[(g * 8 + j) * 4 + d];
    }
    a3 += (float)s.xres[rloc * 4 + d];
    const int r  = r0 + rloc;
    const int n  = r % NN;
    const int bt = r / NN;
    const int t  = bt % NT;
    const int b  = bt / NT;
    if (t < NT - 1) {
      const int oidx = ((b * NN + n) * (NT - 1) + t) * ND + d;
      if (isbf) ((bf16_t*)outp)[oidx] = (bf16_t)a3;
      else      ((float*)outp)[oidx]  = a3;
    }
  }
}

extern "C" void kernel_launch(void* const* d_in, const int* in_sizes, int n_in,
                              void* d_out, int out_size, void* d_ws, size_t ws_size,
                              hipStream_t stream) {
  // d_in[2] rel_rec, d_in[3] rel_send: fixed one-hot structure, computed
  // analytically. d_in[14] pred_steps == 1.
  char* ws = (char*)d_ws;
  bf16_t* cb = (bf16_t*)(ws + 16);             // canonical bf16 arrays + fragments
  float* aggbuf = (float*)(ws + AGG_BYTE_OFF); // 24000*128*4 B = 12.29 MB

  convert_kernel<<<dim3(256), dim3(256), 0, stream>>>(
      d_in[0], d_in[1], d_in[4], d_in[5], d_in[6], d_in[7],
      d_in[8], d_in[9], d_in[10], d_in[11], d_in[12], d_in[13], d_ws);

  edge_kernel<<<dim3(NB * NT * 2), dim3(256), 0, stream>>>(
      cb + C_INPUTS, cb + C_RELTYPE, cb + C_W1F, cb + C_W2F,
      cb + C_B2, aggbuf);

  node_kernel<<<dim3((NB * NT * NN) / 64), dim3(256), 0, stream>>>(
      cb + C_INPUTS, cb + C_OW1F, cb + C_OB1, cb + C_OW2F, cb + C_OB2,
      cb + C_OW3, cb + C_OB3, (const int*)d_ws, aggbuf, d_out);
}

// Round 10
// 384.886 us; speedup vs baseline: 3.2381x; 1.7383x over previous
//
#include <hip/hip_runtime.h>

typedef __bf16 bf16_t;
typedef __bf16 bf16x8 __attribute__((ext_vector_type(8)));
typedef __bf16 bf16x4 __attribute__((ext_vector_type(4)));
typedef float  f32x4  __attribute__((ext_vector_type(4)));

#define NB 16   // B
#define NN 30   // N
#define NT 50   // T
#define ND 4    // D
#define NK 4    // K experts
#define NE 870  // E = N*(N-1)

// canonical workspace layout (element offsets from ws+16, all %8==0 -> 16B aligned)
#define C_INPUTS   0        // 96000
#define C_RELTYPE  96000    // 55680
#define C_B2       152192   // 512
#define C_OB1      152704   // 128
#define C_OB2      152832   // 128
#define C_OW3      152960   // 512
#define C_OB3      153472   // 4 (pad to 8)
#define C_W1F      153480   // 16384  W1 frags [k][ct][quad][lm][j]; b1 folded at quad1,j0
#define C_W2F      169864   // 65536  W2 frags [k][kc][ct][quad*16+lm][j]  (contiguous/frag)
#define C_OW1F     235400   // 20480  oW1 frags [ct][kc(5)][quad][lm][j] (kk>=132 zero)
#define C_OW2F     255880   // 16384  oW2 frags [ct][kc(4)][quad][lm][j]
#define AGG_BYTE_OFF (1u << 20)   // aggbuf (fp32) at ws + 1MB

__device__ __forceinline__ bf16x8 bzero8() {
  bf16x8 z;
#pragma unroll
  for (int j = 0; j < 8; ++j) z[j] = (bf16_t)0.0f;
  return z;
}

__device__ __forceinline__ f32x4 make4(float a, float b, float c, float d) {
  f32x4 v; v[0] = a; v[1] = b; v[2] = c; v[3] = d; return v;
}

// relu + cvt to bf16 + packed 8B store (vector-typed: alias-safe)
__device__ __forceinline__ void pack_store4(bf16_t* dst, f32x4 a) {
  bf16x4 v;
  v[0] = (bf16_t)fmaxf(a[0], 0.0f);
  v[1] = (bf16_t)fmaxf(a[1], 0.0f);
  v[2] = (bf16_t)fmaxf(a[2], 0.0f);
  v[3] = (bf16_t)fmaxf(a[3], 0.0f);
  *(bf16x4*)dst = v;
}

// ---------------------------------------------------------------------------
// dtype detection + canonicalization (bf16) + weight fragment pre-permutation
// ---------------------------------------------------------------------------
__device__ __forceinline__ int detect_isbf16(const void* p) {
  const unsigned short* w = (const unsigned short*)p;
  int c = 0;
#pragma unroll 4
  for (int i = 0; i < 256; i += 2) {
    const int e = (w[i] >> 7) & 0xFF;
    if (e >= 100 && e <= 150) ++c;
  }
  return c >= 96;   // bf16 ~128/128, fp32 ~25/128
}

__device__ __forceinline__ float ldf(const void* src, int idx, int isbf) {
  return isbf ? (float)((const bf16_t*)src)[idx] : ((const float*)src)[idx];
}

__device__ __forceinline__ void conv_arr(const void* src, bf16_t* dst, int n,
                                         int isbf, int gtid, int gsz) {
  if (isbf) {
    const unsigned short* s = (const unsigned short*)src;
    unsigned short* d = (unsigned short*)dst;
    for (int i = gtid; i < n; i += gsz) d[i] = s[i];
  } else {
    const float* s = (const float*)src;
    for (int i = gtid; i < n; i += gsz) dst[i] = (bf16_t)s[i];
  }
}

__global__ void convert_kernel(const void* inputs, const void* rel_type,
                               const void* W1, const void* b1,
                               const void* W2, const void* b2,
                               const void* oW1, const void* ob1,
                               const void* oW2, const void* ob2,
                               const void* oW3, const void* ob3,
                               void* ws)
{
  __shared__ int sflag;
  if (threadIdx.x == 0) sflag = detect_isbf16(inputs);
  __syncthreads();
  const int isbf = sflag;
  if (blockIdx.x == 0 && threadIdx.x == 0) *(int*)ws = isbf;
  bf16_t* cb = (bf16_t*)((char*)ws + 16);
  const int gtid = blockIdx.x * blockDim.x + threadIdx.x;
  const int gsz  = gridDim.x * blockDim.x;

  conv_arr(inputs,   cb + C_INPUTS,  96000, isbf, gtid, gsz);
  conv_arr(rel_type, cb + C_RELTYPE, 55680, isbf, gtid, gsz);
  conv_arr(b2,  cb + C_B2,  512, isbf, gtid, gsz);
  conv_arr(ob1, cb + C_OB1, 128, isbf, gtid, gsz);
  conv_arr(ob2, cb + C_OB2, 128, isbf, gtid, gsz);
  conv_arr(oW3, cb + C_OW3, 512, isbf, gtid, gsz);
  conv_arr(ob3, cb + C_OB3, 4,   isbf, gtid, gsz);

  // W1 fragments: idx = (((k*8+ct)*4+quad)*16+lm)*8+j
  // quad==0: W1[k][kk=j][n]; quad==1 && j==0: b1[k][n] (bias feature kk=8); else 0
  for (int i = gtid; i < 16384; i += gsz) {
    const int j = i & 7, lm = (i >> 3) & 15, quad = (i >> 7) & 3;
    const int ct = (i >> 9) & 7, k = (i >> 12) & 3;
    float v = 0.0f;
    if (quad == 0)                 v = ldf(W1, k * 1024 + j * 128 + ct * 16 + lm, isbf);
    else if (quad == 1 && j == 0)  v = ldf(b1, k * 128 + ct * 16 + lm, isbf);
    cb[C_W1F + i] = (bf16_t)v;
  }
  // W2 fragments, per-(kc,ct) contiguous: idx = (((k*4+kc)*8+ct)*64 + quad*16+lm)*8 + j
  for (int i = gtid; i < 65536; i += gsz) {
    const int j = i & 7;
    const int l64 = (i >> 3) & 63;          // quad*16+lm
    const int ct = (i >> 9) & 7, kc = (i >> 12) & 3, k = (i >> 14) & 3;
    const int quad = l64 >> 4, lm = l64 & 15;
    const int kk = kc * 32 + quad * 8 + j;
    cb[C_W2F + i] = (bf16_t)ldf(W2, k * 16384 + kk * 128 + ct * 16 + lm, isbf);
  }
  // oW1 fragments: idx = (((ct*5+kc)*4+quad)*16+lm)*8+j ; kk>=132 -> 0
  for (int i = gtid; i < 20480; i += gsz) {
    const int j = i & 7, lm = (i >> 3) & 15, quad = (i >> 7) & 3;
    const int rem = i >> 9;              // 0..39
    const int kc = rem % 5, ct = rem / 5;
    const int kk = kc * 32 + quad * 8 + j;
    float v = 0.0f;
    if (kk < 132) v = ldf(oW1, kk * 128 + ct * 16 + lm, isbf);
    cb[C_OW1F + i] = (bf16_t)v;
  }
  // oW2 fragments: idx = (((ct*4+kc)*4+quad)*16+lm)*8+j
  for (int i = gtid; i < 16384; i += gsz) {
    const int j = i & 7, lm = (i >> 3) & 15, quad = (i >> 7) & 3;
    const int kc = (i >> 9) & 3, ct = (i >> 11) & 7;
    const int kk = kc * 32 + quad * 8 + j;
    cb[C_OW2F + i] = (bf16_t)ldf(oW2, kk * 128 + ct * 16 + lm, isbf);
  }
}

// ---------------------------------------------------------------------------
// Edge kernel v2: aggregation as MFMA (agg = S*M), no shuffles/atomics/seg
// logic in the hot loop. 7 tiles of 64 edges (no node alignment needed).
// Wave w: output cols ct in [(w&1)*4,+4), edge strips 2*(w>>1)..+1, and
// agg K-chunk (w>>1). agg accumulates in 16 persistent VGPRs across tiles+k;
// one LDS-atomic combine at the end. S A-fragments in LDS: zeros written
// once, 435 nonzero slots re-scattered per k (positions k-invariant).
// agg-GEMM of tile t fused into layer-1 phase of tile t+1 (disjoint LDS).
// ---------------------------------------------------------------------------
struct EdgeSmem {
  bf16_t h[8192];                                   // 16384 B  h1 A-frags [strip][kc][q*16+lm][j]
  union { bf16_t m[128 * 68]; float aggf[2048]; } mb; // 17408 B  M B-frag buf [m][e(64)+pad4] / final agg
  bf16_t sfrag[7168];                               // 14336 B  S A-frags [chunk14][lane64][j8]
  bf16_t xl[128];                                   // 256 B    x[b,t,:,:]
};                                                   // 48384 B -> 3 blocks/CU

__device__ __forceinline__ void agg_step(const EdgeSmem& s, int chunkid, int ctbase,
                                         int quad, int lm, int lane, int mychunk,
                                         f32x4* aggacc) {
  const bf16x8 sa = *(const bf16x8*)&s.sfrag[(chunkid * 64 + lane) * 8];
#pragma unroll
  for (int c = 0; c < 4; ++c) {
    const bf16x8 mbf = *(const bf16x8*)&s.mb.m[((ctbase + c) * 16 + lm) * 68 + mychunk * 32 + quad * 8];
    aggacc[c] = __builtin_amdgcn_mfma_f32_16x16x32_bf16(sa, mbf, aggacc[c], 0, 0, 0);
  }
}

__global__ __launch_bounds__(256)
void edge_kernel(const bf16_t* __restrict__ inputs,
                 const bf16_t* __restrict__ rel_type,
                 const bf16_t* __restrict__ w1f_g,
                 const bf16_t* __restrict__ w2f_g,
                 const bf16_t* __restrict__ b2c,
                 float* __restrict__ aggbuf)
{
  __shared__ EdgeSmem s;
  const int tid  = threadIdx.x;
  const int bid  = blockIdx.x;
  const int nhalf = bid & 1;
  const int bt   = bid >> 1;
  const int b    = bt / NT;
  const int t    = bt - b * NT;
  const int wave = tid >> 6;
  const int lane = tid & 63;
  const int quad = lane >> 4;
  const int lm   = lane & 15;
  const int ctbase  = (wave & 1) * 4;    // output-col half
  const int spair   = (wave >> 1) * 2;   // first edge strip of this wave
  const int mychunk = wave >> 1;         // agg K-chunk within tile

  // ---- one-time staging ----
  if (tid < 30) {
    *(uint2*)&s.xl[tid * 4] = *(const uint2*)&inputs[((b * NN + tid) * NT + t) * ND];
  }
  for (int i = tid; i < 896; i += 256) *(bf16x8*)&s.sfrag[i * 8] = bzero8();
  __syncthreads();

  const int e0g = b * NE + nhalf * 435;
  f32x4 aggacc[4];
#pragma unroll
  for (int c = 0; c < 4; ++c) aggacc[c] = make4(0.f, 0.f, 0.f, 0.f);

#pragma unroll 1
  for (int k = 0; k < NK; ++k) {
    // ---- per-k hoist (80 regs) + b2 ----
    bf16x8 w1r[4];
    bf16x8 w2r[4][4];
    float  b2s[4];
#pragma unroll
    for (int c = 0; c < 4; ++c) {
      const int ct = ctbase + c;
      w1r[c] = *(const bf16x8*)&w1f_g[(((k * 8 + ct) * 4 + quad) * 16 + lm) * 8];
#pragma unroll
      for (int kc = 0; kc < 4; ++kc)
        w2r[c][kc] = *(const bf16x8*)&w2f_g[((((k * 4 + kc) * 8) + ct) * 64 + quad * 16 + lm) * 8];
      b2s[c] = (float)b2c[k * 128 + ct * 16 + lm];
    }
    // ---- scatter S(k): 435 nonzero slots (first read is 2+ barriers away) ----
    for (int i = tid; i < 435; i += 256) {
      const int n = i / 29;                       // local receiver row 0..14
      const int slot = (((i >> 5) * 4 + ((i >> 3) & 3)) * 16 + n) * 8 + (i & 7);
      s.sfrag[slot] = rel_type[(e0g + i) * 4 + k];
    }

#pragma unroll 1
    for (int tt = 0; tt < 7; ++tt) {
      // ---- agg-GEMM of previous tile (reads sfrag+mb, writes regs only) ----
      if (tt > 0) agg_step(s, (tt - 1) * 2 + mychunk, ctbase, quad, lm, lane, mychunk, aggacc);

      // ---- layer 1: both strips, my 64 output cols ----
#pragma unroll
      for (int si = 0; si < 2; ++si) {
        const int strip = spair + si;
        const int rr = strip * 16 + lm;
        const int e  = tt * 64 + rr;             // edge local to half
        bf16x8 pm = bzero8();
        if (quad == 0) {
          if (e < 435) {
            const int recv = nhalf * 15 + e / 29;
            const int j29  = e % 29;
            const int send = j29 + (j29 >= recv);
            union { uint2 u2[2]; bf16x8 v; } c;
            c.u2[0] = *(const uint2*)&s.xl[recv * 4];
            c.u2[1] = *(const uint2*)&s.xl[send * 4];
            pm = c.v;
          }
        } else if (quad == 1) {
          pm[0] = (bf16_t)1.0f;                  // bias feature: W1F row kk=8 holds b1
        }
        const f32x4 z4 = make4(0.0f, 0.0f, 0.0f, 0.0f);
#pragma unroll
        for (int c = 0; c < 4; ++c) {
          const int ct = ctbase + c;
          f32x4 a1 = __builtin_amdgcn_mfma_f32_16x16x32_bf16(w1r[c], pm, z4, 0, 0, 0);
          // C-layout -> h A-fragment slot (R9-verified bijection)
          const int qr = 2 * (ct & 1) + (quad >> 1);
          pack_store4(&s.h[((strip * 4 + (ct >> 1)) * 64 + qr * 16 + lm) * 8 + 4 * (quad & 1)], a1);
        }
      }
      __syncthreads();   // h complete (written across wave pairs)

      // ---- layer 2 -> M fragments (relu baked in) ----
#pragma unroll
      for (int si = 0; si < 2; ++si) {
        const int strip = spair + si;
        bf16x8 af[4];
#pragma unroll
        for (int kc = 0; kc < 4; ++kc)
          af[kc] = *(const bf16x8*)&s.h[((strip * 4 + kc) * 64 + quad * 16 + lm) * 8];
#pragma unroll
        for (int c = 0; c < 4; ++c) {
          f32x4 acc = make4(b2s[c], b2s[c], b2s[c], b2s[c]);
#pragma unroll
          for (int kc = 0; kc < 4; ++kc)
            acc = __builtin_amdgcn_mfma_f32_16x16x32_bf16(af[kc], w2r[c][kc], acc, 0, 0, 0);
          // D[e=strip*16+quad*4+r][m=(ctbase+c)*16+lm] -> mb[m][e], 4 consecutive e
          pack_store4(&s.mb.m[((ctbase + c) * 16 + lm) * 68 + strip * 16 + quad * 4], acc);
        }
      }
      __syncthreads();   // M complete; next iteration may run agg + overwrite h
    }
    agg_step(s, 12 + mychunk, ctbase, quad, lm, lane, mychunk, aggacc);
    __syncthreads();     // agg reads done before next k's S scatter / M overwrite
  }

  // ---- finalize: combine wave-pair partials, write agg to global ----
  for (int i = tid; i < 2048; i += 256) s.mb.aggf[i] = 0.0f;
  __syncthreads();
#pragma unroll
  for (int c = 0; c < 4; ++c)
#pragma unroll
    for (int r = 0; r < 4; ++r)
      atomicAdd(&s.mb.aggf[(quad * 4 + r) * 128 + (ctbase + c) * 16 + lm], aggacc[c][r]);
  __syncthreads();
  for (int i = tid; i < 15 * 128; i += 256) {
    const int r = i >> 7, col = i & 127;
    aggbuf[(size_t)(bt * NN + nhalf * 15 + r) * 128 + col] = s.mb.aggf[r * 128 + col];
  }
}

// ---------------------------------------------------------------------------
// Node kernel: 64 node-instances per block; weights loaded at use (L2-hot),
// ~60 live regs, wave-private h1/h2, single initial barrier (R8/R9-verified).
// ---------------------------------------------------------------------------
struct NodeSmem {
  bf16_t h1[64 * 136];     // 17408 B
  bf16_t h2[64 * 136];     // 17408 B
  bf16_t xres[64 * 4];
  float  b1f[128];
  float  b2f[128];
  float  w3f[128 * 4];
  float  b3f[4];
};                          // ~38.4 KB

__global__ __launch_bounds__(256)
void node_kernel(const bf16_t* __restrict__ inputs,
                 const bf16_t* __restrict__ ow1f_g, const bf16_t* __restrict__ ob1,
                 const bf16_t* __restrict__ ow2f_g, const bf16_t* __restrict__ ob2,
                 const bf16_t* __restrict__ oW3, const bf16_t* __restrict__ ob3,
                 const int* __restrict__ flagptr,
                 const float* __restrict__ aggbuf,
                 void* __restrict__ outp)
{
  __shared__ NodeSmem s;
  const int tid  = threadIdx.x;
  const int wave = tid >> 6;
  const int lane = tid & 63;
  const int quad = lane >> 4;
  const int lm   = lane & 15;
  const int row  = wave * 16 + lm;
  const int r0   = blockIdx.x * 64;
  const int isbf = *flagptr;

  // ---- one-time staging (single barrier) ----
  if (tid < 64) {
    const int r  = r0 + tid;
    const int n  = r % NN;
    const int bt = r / NN;
    const int t  = bt % NT;
    const int b  = bt / NT;
    *(uint2*)&s.xres[tid * 4] = *(const uint2*)&inputs[((b * NN + n) * NT + t) * ND];
  }
  if (tid < 128) s.b1f[tid] = (float)ob1[tid];
  else           s.b2f[tid - 128] = (float)ob2[tid - 128];
  if (tid < 4) s.b3f[tid] = (float)ob3[tid];
  for (int i = tid; i < 512; i += 256) s.w3f[i] = (float)oW3[i];
  __syncthreads();

  // ---- build aug B-fragments directly from global agg (fp32) + x ----
  bf16x8 bfa[5];
  {
    const float* aggrow = aggbuf + (size_t)(r0 + row) * 128;
    float tmp[8];
    if (quad == 0) {
#pragma unroll
      for (int j = 0; j < 4; ++j) tmp[j] = (float)s.xres[row * 4 + j];
      const float4 a = *(const float4*)(aggrow);
      tmp[4] = a.x; tmp[5] = a.y; tmp[6] = a.z; tmp[7] = a.w;
    } else {
      const int c0 = quad * 8 - 4;
      const float4 a = *(const float4*)(aggrow + c0);
      const float4 d = *(const float4*)(aggrow + c0 + 4);
      tmp[0] = a.x; tmp[1] = a.y; tmp[2] = a.z; tmp[3] = a.w;
      tmp[4] = d.x; tmp[5] = d.y; tmp[6] = d.z; tmp[7] = d.w;
    }
#pragma unroll
    for (int j = 0; j < 8; ++j) bfa[0][j] = (bf16_t)tmp[j];
#pragma unroll
    for (int kc = 1; kc < 4; ++kc) {
      const int c0 = kc * 32 + quad * 8 - 4;
      const float4 a = *(const float4*)(aggrow + c0);
      const float4 d = *(const float4*)(aggrow + c0 + 4);
      tmp[0] = a.x; tmp[1] = a.y; tmp[2] = a.z; tmp[3] = a.w;
      tmp[4] = d.x; tmp[5] = d.y; tmp[6] = d.z; tmp[7] = d.w;
#pragma unroll
      for (int j = 0; j < 8; ++j) bfa[kc][j] = (bf16_t)tmp[j];
    }
    if (quad == 0) {
      const float4 a = *(const float4*)(aggrow + 124);
      tmp[0] = a.x; tmp[1] = a.y; tmp[2] = a.z; tmp[3] = a.w;
      tmp[4] = 0.f; tmp[5] = 0.f; tmp[6] = 0.f; tmp[7] = 0.f;
#pragma unroll
      for (int j = 0; j < 8; ++j) bfa[4][j] = (bf16_t)tmp[j];
    } else bfa[4] = bzero8();
  }

  // ---- layer 1 (swapped), weights at use: h1[row][n] ----
#pragma unroll
  for (int ct = 0; ct < 8; ++ct) {
    const int nb = ct * 16 + quad * 4;
    f32x4 acc = make4(s.b1f[nb], s.b1f[nb + 1], s.b1f[nb + 2], s.b1f[nb + 3]);
#pragma unroll
    for (int kc = 0; kc < 5; ++kc) {
      const bf16x8 w = *(const bf16x8*)&ow1f_g[(((ct * 5 + kc) * 4 + quad) * 16 + lm) * 8];
      acc = __builtin_amdgcn_mfma_f32_16x16x32_bf16(w, bfa[kc], acc, 0, 0, 0);
    }
    pack_store4(&s.h1[row * 136 + ct * 16 + quad * 4], acc);
  }
  // no barrier: h1 rows are wave-private

  bf16x8 af[4];
#pragma unroll
  for (int kc = 0; kc < 4; ++kc)
    af[kc] = *(const bf16x8*)&s.h1[row * 136 + kc * 32 + quad * 8];

  // ---- layer 2 (swapped), weights at use: h2[row][m] ----
#pragma unroll
  for (int ct = 0; ct < 8; ++ct) {
    const int mb = ct * 16 + quad * 4;
    f32x4 acc = make4(s.b2f[mb], s.b2f[mb + 1], s.b2f[mb + 2], s.b2f[mb + 3]);
#pragma unroll
    for (int kc = 0; kc < 4; ++kc) {
      const bf16x8 w = *(const bf16x8*)&ow2f_g[(((ct * 4 + kc) * 4 + quad) * 16 + lm) * 8];
      acc = __builtin_amdgcn_mfma_f32_16x16x32_bf16(w, af[kc], acc, 0, 0, 0);
    }
    pack_store4(&s.h2[row * 136 + ct * 16 + quad * 4], acc);
  }
  // no barrier: layer-3 lanes read their own wave's rows

  // ---- layer 3 (VALU) + residual + store ----
  {
    const int rloc = tid >> 2;
    const int d    = tid & 3;
    float a3 = s.b3f[d];
#pragma unroll
    for (int g = 0; g < 16; ++g) {
      const bf16x8 hv = *(const bf16x8*)&s.h2[rloc * 136 + g * 8];
#pragma unroll
      for (int j = 0; j < 8; ++j)
        a3 += (float)hv[j] * s.w3f[(g * 8 + j) * 4 + d];
    }
    a3 += (float)s.xres[rloc * 4 + d];
    const int r  = r0 + rloc;
    const int n  = r % NN;
    const int bt = r / NN;
    const int t  = bt % NT;
    const int b  = bt / NT;
    if (t < NT - 1) {
      const int oidx = ((b * NN + n) * (NT - 1) + t) * ND + d;
      if (isbf) ((bf16_t*)outp)[oidx] = (bf16_t)a3;
      else      ((float*)outp)[oidx]  = a3;
    }
  }
}

extern "C" void kernel_launch(void* const* d_in, const int* in_sizes, int n_in,
                              void* d_out, int out_size, void* d_ws, size_t ws_size,
                              hipStream_t stream) {
  // d_in[2] rel_rec, d_in[3] rel_send: fixed one-hot structure, computed
  // analytically. d_in[14] pred_steps == 1.
  char* ws = (char*)d_ws;
  bf16_t* cb = (bf16_t*)(ws + 16);             // canonical bf16 arrays + fragments
  float* aggbuf = (float*)(ws + AGG_BYTE_OFF); // 24000*128*4 B = 12.29 MB

  convert_kernel<<<dim3(256), dim3(256), 0, stream>>>(
      d_in[0], d_in[1], d_in[4], d_in[5], d_in[6], d_in[7],
      d_in[8], d_in[9], d_in[10], d_in[11], d_in[12], d_in[13], d_ws);

  edge_kernel<<<dim3(NB * NT * 2), dim3(256), 0, stream>>>(
      cb + C_INPUTS, cb + C_RELTYPE, cb + C_W1F, cb + C_W2F,
      cb + C_B2, aggbuf);

  node_kernel<<<dim3((NB * NT * NN) / 64), dim3(256), 0, stream>>>(
      cb + C_INPUTS, cb + C_OW1F, cb + C_OB1, cb + C_OW2F, cb + C_OB2,
      cb + C_OW3, cb + C_OB3, (const int*)d_ws, aggbuf, d_out);
}

// Round 11
// 345.470 us; speedup vs baseline: 3.6075x; 1.1141x over previous
//
#include <hip/hip_runtime.h>

typedef __bf16 bf16_t;
typedef __bf16 bf16x8 __attribute__((ext_vector_type(8)));
typedef __bf16 bf16x4 __attribute__((ext_vector_type(4)));
typedef float  f32x4  __attribute__((ext_vector_type(4)));

#define NB 16   // B
#define NN 30   // N
#define NT 50   // T
#define ND 4    // D
#define NK 4    // K experts
#define NE 870  // E = N*(N-1)

// canonical workspace layout (element offsets from ws+16, all %8==0 -> 16B aligned)
#define C_INPUTS   0        // 96000
#define C_RELTYPE  96000    // 55680
#define C_B2       152192   // 512
#define C_OB1      152704   // 128
#define C_OB2      152832   // 128
#define C_OW3      152960   // 512
#define C_OB3      153472   // 4 (pad to 8)
#define C_W1F      153480   // 16384  W1 frags [k][ct][quad][lm][j]; b1 folded at quad1,j0
#define C_W2F      169864   // 65536  W2 frags [k][kc][ct][quad*16+lm][j]  (contiguous/frag)
#define C_OW1F     235400   // 20480  oW1 frags [ct][kc(5)][quad][lm][j] (kk>=132 zero)
#define C_OW2F     255880   // 16384  oW2 frags [ct][kc(4)][quad][lm][j]
#define AGG_BYTE_OFF (1u << 20)   // aggbuf (fp32) at ws + 1MB

__device__ __forceinline__ bf16x8 bzero8() {
  bf16x8 z;
#pragma unroll
  for (int j = 0; j < 8; ++j) z[j] = (bf16_t)0.0f;
  return z;
}

__device__ __forceinline__ f32x4 make4(float a, float b, float c, float d) {
  f32x4 v; v[0] = a; v[1] = b; v[2] = c; v[3] = d; return v;
}

// relu + cvt to bf16 + packed 8B store (vector-typed: alias-safe)
__device__ __forceinline__ void pack_store4(bf16_t* dst, f32x4 a) {
  bf16x4 v;
  v[0] = (bf16_t)fmaxf(a[0], 0.0f);
  v[1] = (bf16_t)fmaxf(a[1], 0.0f);
  v[2] = (bf16_t)fmaxf(a[2], 0.0f);
  v[3] = (bf16_t)fmaxf(a[3], 0.0f);
  *(bf16x4*)dst = v;
}

// ---------------------------------------------------------------------------
// dtype detection + canonicalization (bf16) + weight fragment pre-permutation
// ---------------------------------------------------------------------------
__device__ __forceinline__ int detect_isbf16(const void* p) {
  const unsigned short* w = (const unsigned short*)p;
  int c = 0;
#pragma unroll 4
  for (int i = 0; i < 256; i += 2) {
    const int e = (w[i] >> 7) & 0xFF;
    if (e >= 100 && e <= 150) ++c;
  }
  return c >= 96;   // bf16 ~128/128, fp32 ~25/128
}

__device__ __forceinline__ float ldf(const void* src, int idx, int isbf) {
  return isbf ? (float)((const bf16_t*)src)[idx] : ((const float*)src)[idx];
}

__device__ __forceinline__ void conv_arr(const void* src, bf16_t* dst, int n,
                                         int isbf, int gtid, int gsz) {
  if (isbf) {
    const unsigned short* s = (const unsigned short*)src;
    unsigned short* d = (unsigned short*)dst;
    for (int i = gtid; i < n; i += gsz) d[i] = s[i];
  } else {
    const float* s = (const float*)src;
    for (int i = gtid; i < n; i += gsz) dst[i] = (bf16_t)s[i];
  }
}

__global__ void convert_kernel(const void* inputs, const void* rel_type,
                               const void* W1, const void* b1,
                               const void* W2, const void* b2,
                               const void* oW1, const void* ob1,
                               const void* oW2, const void* ob2,
                               const void* oW3, const void* ob3,
                               void* ws)
{
  __shared__ int sflag;
  if (threadIdx.x == 0) sflag = detect_isbf16(inputs);
  __syncthreads();
  const int isbf = sflag;
  if (blockIdx.x == 0 && threadIdx.x == 0) *(int*)ws = isbf;
  bf16_t* cb = (bf16_t*)((char*)ws + 16);
  const int gtid = blockIdx.x * blockDim.x + threadIdx.x;
  const int gsz  = gridDim.x * blockDim.x;

  conv_arr(inputs,   cb + C_INPUTS,  96000, isbf, gtid, gsz);
  conv_arr(rel_type, cb + C_RELTYPE, 55680, isbf, gtid, gsz);
  conv_arr(b2,  cb + C_B2,  512, isbf, gtid, gsz);
  conv_arr(ob1, cb + C_OB1, 128, isbf, gtid, gsz);
  conv_arr(ob2, cb + C_OB2, 128, isbf, gtid, gsz);
  conv_arr(oW3, cb + C_OW3, 512, isbf, gtid, gsz);
  conv_arr(ob3, cb + C_OB3, 4,   isbf, gtid, gsz);

  // W1 fragments: idx = (((k*8+ct)*4+quad)*16+lm)*8+j
  // quad==0: W1[k][kk=j][n]; quad==1 && j==0: b1[k][n] (bias feature kk=8); else 0
  for (int i = gtid; i < 16384; i += gsz) {
    const int j = i & 7, lm = (i >> 3) & 15, quad = (i >> 7) & 3;
    const int ct = (i >> 9) & 7, k = (i >> 12) & 3;
    float v = 0.0f;
    if (quad == 0)                 v = ldf(W1, k * 1024 + j * 128 + ct * 16 + lm, isbf);
    else if (quad == 1 && j == 0)  v = ldf(b1, k * 128 + ct * 16 + lm, isbf);
    cb[C_W1F + i] = (bf16_t)v;
  }
  // W2 fragments, per-(kc,ct) contiguous: idx = (((k*4+kc)*8+ct)*64 + quad*16+lm)*8 + j
  for (int i = gtid; i < 65536; i += gsz) {
    const int j = i & 7;
    const int l64 = (i >> 3) & 63;          // quad*16+lm
    const int ct = (i >> 9) & 7, kc = (i >> 12) & 3, k = (i >> 14) & 3;
    const int quad = l64 >> 4, lm = l64 & 15;
    const int kk = kc * 32 + quad * 8 + j;
    cb[C_W2F + i] = (bf16_t)ldf(W2, k * 16384 + kk * 128 + ct * 16 + lm, isbf);
  }
  // oW1 fragments: idx = (((ct*5+kc)*4+quad)*16+lm)*8+j ; kk>=132 -> 0
  for (int i = gtid; i < 20480; i += gsz) {
    const int j = i & 7, lm = (i >> 3) & 15, quad = (i >> 7) & 3;
    const int rem = i >> 9;              // 0..39
    const int kc = rem % 5, ct = rem / 5;
    const int kk = kc * 32 + quad * 8 + j;
    float v = 0.0f;
    if (kk < 132) v = ldf(oW1, kk * 128 + ct * 16 + lm, isbf);
    cb[C_OW1F + i] = (bf16_t)v;
  }
  // oW2 fragments: idx = (((ct*4+kc)*4+quad)*16+lm)*8+j
  for (int i = gtid; i < 16384; i += gsz) {
    const int j = i & 7, lm = (i >> 3) & 15, quad = (i >> 7) & 3;
    const int kc = (i >> 9) & 3, ct = (i >> 11) & 7;
    const int kk = kc * 32 + quad * 8 + j;
    cb[C_OW2F + i] = (bf16_t)ldf(oW2, kk * 128 + ct * 16 + lm, isbf);
  }
}

// ---------------------------------------------------------------------------
// Edge kernel v3: no m-buffer. The layer-2 C-output IS the B-fragment of a
// K-padded (j<4 real, j>=4 zero on both A and B) 16x16x32 agg MFMA per
// (strip, ct): relu+pack the L2 acc into the low half of a bf16x8, pair with
// a per-strip S-fragment from LDS (one sequential ds_read_b64), accumulate
// into persistent aggacc regs. Removes R10's 4-way-conflicted m writes/reads,
// 17.4 KB of LDS (31 KB total -> 4 blocks/CU), and the rt4 buffer.
// sfrag: [gstrip(28)][lane(64)][j(4)] = S[n=lm][e=gstrip*16+quad*4+j],
// zero-initialized once; 435 slots re-scattered per k.
// ---------------------------------------------------------------------------
struct EdgeSmem {
  union { bf16_t h[8192]; float aggf[2048]; } u;   // 16384 B  h1 A-frags / final agg
  bf16_t sfrag[7168];                              // 14336 B  S A-frags (j<4 real)
  bf16_t xl[128];                                  // 256 B    x[b,t,:,:]
};                                                  // 30976 B -> 4 blocks/CU (VGPR-capped)

__global__ __launch_bounds__(256)
void edge_kernel(const bf16_t* __restrict__ inputs,
                 const bf16_t* __restrict__ rel_type,
                 const bf16_t* __restrict__ w1f_g,
                 const bf16_t* __restrict__ w2f_g,
                 const bf16_t* __restrict__ b2c,
                 float* __restrict__ aggbuf)
{
  __shared__ EdgeSmem s;
  const int tid  = threadIdx.x;
  const int bid  = blockIdx.x;
  const int nhalf = bid & 1;
  const int bt   = bid >> 1;
  const int b    = bt / NT;
  const int t    = bt - b * NT;
  const int wave = tid >> 6;
  const int lane = tid & 63;
  const int quad = lane >> 4;
  const int lm   = lane & 15;
  const int ctbase = (wave & 1) * 4;     // output-col half
  const int spair  = (wave >> 1) * 2;    // first edge strip of this wave

  // ---- one-time staging ----
  if (tid < 30) {
    *(uint2*)&s.xl[tid * 4] = *(const uint2*)&inputs[((b * NN + tid) * NT + t) * ND];
  }
  for (int i = tid; i < 896; i += 256) *(bf16x8*)&s.sfrag[i * 8] = bzero8();
  __syncthreads();

  const int e0g = b * NE + nhalf * 435;
  f32x4 aggacc[4];
#pragma unroll
  for (int c = 0; c < 4; ++c) aggacc[c] = make4(0.f, 0.f, 0.f, 0.f);

#pragma unroll 1
  for (int k = 0; k < NK; ++k) {
    // ---- per-k hoist (80 regs), fully-contiguous L2-hot loads ----
    bf16x8 w1r[4];
    bf16x8 w2r[4][4];
    float  b2s[4];
#pragma unroll
    for (int c = 0; c < 4; ++c) {
      const int ct = ctbase + c;
      w1r[c] = *(const bf16x8*)&w1f_g[(((k * 8 + ct) * 4 + quad) * 16 + lm) * 8];
#pragma unroll
      for (int kc = 0; kc < 4; ++kc)
        w2r[c][kc] = *(const bf16x8*)&w2f_g[((((k * 4 + kc) * 8) + ct) * 64 + quad * 16 + lm) * 8];
      b2s[c] = (float)b2c[k * 128 + ct * 16 + lm];
    }
    // ---- scatter S(k): 435 slots; edge i -> strip i>>4, q=(i>>2)&3, j=i&3, n=i/29
    // (safe: after prior tile's final barrier, before this k's first L1 barrier)
    for (int i = tid; i < 435; i += 256) {
      const int slot = ((i >> 4) * 64 + ((i >> 2) & 3) * 16 + i / 29) * 4 + (i & 3);
      s.sfrag[slot] = rel_type[(e0g + i) * 4 + k];
    }

#pragma unroll 1
    for (int tt = 0; tt < 7; ++tt) {
      // ---- layer 1: both strips of the pair, my 64 output cols ----
#pragma unroll
      for (int si = 0; si < 2; ++si) {
        const int strip = spair + si;
        const int rr = strip * 16 + lm;
        const int e  = tt * 64 + rr;             // edge local to half
        bf16x8 pm = bzero8();
        if (quad == 0) {
          if (e < 435) {
            const int recv = nhalf * 15 + e / 29;
            const int j29  = e % 29;
            const int send = j29 + (j29 >= recv);
            union { uint2 u2[2]; bf16x8 v; } c;
            c.u2[0] = *(const uint2*)&s.xl[recv * 4];
            c.u2[1] = *(const uint2*)&s.xl[send * 4];
            pm = c.v;
          }
        } else if (quad == 1) {
          pm[0] = (bf16_t)1.0f;                  // bias feature: W1F row kk=8 holds b1
        }
        const f32x4 z4 = make4(0.0f, 0.0f, 0.0f, 0.0f);
#pragma unroll
        for (int c = 0; c < 4; ++c) {
          const int ct = ctbase + c;
          f32x4 a1 = __builtin_amdgcn_mfma_f32_16x16x32_bf16(w1r[c], pm, z4, 0, 0, 0);
          // C-layout -> h A-fragment slot (R9/R10-verified bijection)
          const int qr = 2 * (ct & 1) + (quad >> 1);
          pack_store4(&s.u.h[((strip * 4 + (ct >> 1)) * 64 + qr * 16 + lm) * 8 + 4 * (quad & 1)], a1);
        }
      }
      __syncthreads();   // h complete (written across wave pairs)

      // ---- layer 2 + in-register agg (K-padded 16x16x32, j>=4 zero) ----
#pragma unroll
      for (int si = 0; si < 2; ++si) {
        const int strip = spair + si;
        bf16x8 af[4];
#pragma unroll
        for (int kc = 0; kc < 4; ++kc)
          af[kc] = *(const bf16x8*)&s.u.h[((strip * 4 + kc) * 64 + quad * 16 + lm) * 8];
        // S A-fragment: S[n=lm][e=strip*16+quad*4+j], j<4; upper half zero
        bf16x8 sa = bzero8();
        {
          const bf16x4 s4 = *(const bf16x4*)&s.sfrag[((tt * 4 + strip) * 64 + lane) * 4];
          sa[0] = s4[0]; sa[1] = s4[1]; sa[2] = s4[2]; sa[3] = s4[3];
        }
#pragma unroll
        for (int c = 0; c < 4; ++c) {
          f32x4 acc = make4(b2s[c], b2s[c], b2s[c], b2s[c]);
#pragma unroll
          for (int kc = 0; kc < 4; ++kc)
            acc = __builtin_amdgcn_mfma_f32_16x16x32_bf16(af[kc], w2r[c][kc], acc, 0, 0, 0);
          // D[e=strip*16+quad*4+r][m] is exactly the agg B-fragment (k=quad*8+r)
          bf16x8 mb = bzero8();
          mb[0] = (bf16_t)fmaxf(acc[0], 0.0f);
          mb[1] = (bf16_t)fmaxf(acc[1], 0.0f);
          mb[2] = (bf16_t)fmaxf(acc[2], 0.0f);
          mb[3] = (bf16_t)fmaxf(acc[3], 0.0f);
          aggacc[c] = __builtin_amdgcn_mfma_f32_16x16x32_bf16(sa, mb, aggacc[c], 0, 0, 0);
        }
      }
      __syncthreads();   // h consumed; next tile may overwrite
    }
  }

  // ---- finalize: combine wave partials, write agg to global ----
  for (int i = tid; i < 2048; i += 256) s.u.aggf[i] = 0.0f;
  __syncthreads();
#pragma unroll
  for (int c = 0; c < 4; ++c)
#pragma unroll
    for (int r = 0; r < 4; ++r)
      atomicAdd(&s.u.aggf[(quad * 4 + r) * 128 + (ctbase + c) * 16 + lm], aggacc[c][r]);
  __syncthreads();
  for (int i = tid; i < 15 * 128; i += 256) {
    const int r = i >> 7, col = i & 127;
    aggbuf[(size_t)(bt * NN + nhalf * 15 + r) * 128 + col] = s.u.aggf[r * 128 + col];
  }
}

// ---------------------------------------------------------------------------
// Node kernel: 64 node-instances per block; weights loaded at use (L2-hot),
// ~60 live regs, wave-private h1/h2, single initial barrier (R8-R10 verified).
// ---------------------------------------------------------------------------
struct NodeSmem {
  bf16_t h1[64 * 136];     // 17408 B
  bf16_t h2[64 * 136];     // 17408 B
  bf16_t xres[64 * 4];
  float  b1f[128];
  float  b2f[128];
  float  w3f[128 * 4];
  float  b3f[4];
};                          // ~38.4 KB

__global__ __launch_bounds__(256)
void node_kernel(const bf16_t* __restrict__ inputs,
                 const bf16_t* __restrict__ ow1f_g, const bf16_t* __restrict__ ob1,
                 const bf16_t* __restrict__ ow2f_g, const bf16_t* __restrict__ ob2,
                 const bf16_t* __restrict__ oW3, const bf16_t* __restrict__ ob3,
                 const int* __restrict__ flagptr,
                 const float* __restrict__ aggbuf,
                 void* __restrict__ outp)
{
  __shared__ NodeSmem s;
  const int tid  = threadIdx.x;
  const int wave = tid >> 6;
  const int lane = tid & 63;
  const int quad = lane >> 4;
  const int lm   = lane & 15;
  const int row  = wave * 16 + lm;
  const int r0   = blockIdx.x * 64;
  const int isbf = *flagptr;

  // ---- one-time staging (single barrier) ----
  if (tid < 64) {
    const int r  = r0 + tid;
    const int n  = r % NN;
    const int bt = r / NN;
    const int t  = bt % NT;
    const int b  = bt / NT;
    *(uint2*)&s.xres[tid * 4] = *(const uint2*)&inputs[((b * NN + n) * NT + t) * ND];
  }
  if (tid < 128) s.b1f[tid] = (float)ob1[tid];
  else           s.b2f[tid - 128] = (float)ob2[tid - 128];
  if (tid < 4) s.b3f[tid] = (float)ob3[tid];
  for (int i = tid; i < 512; i += 256) s.w3f[i] = (float)oW3[i];
  __syncthreads();

  // ---- build aug B-fragments directly from global agg (fp32) + x ----
  bf16x8 bfa[5];
  {
    const float* aggrow = aggbuf + (size_t)(r0 + row) * 128;
    float tmp[8];
    if (quad == 0) {
#pragma unroll
      for (int j = 0; j < 4; ++j) tmp[j] = (float)s.xres[row * 4 + j];
      const float4 a = *(const float4*)(aggrow);
      tmp[4] = a.x; tmp[5] = a.y; tmp[6] = a.z; tmp[7] = a.w;
    } else {
      const int c0 = quad * 8 - 4;
      const float4 a = *(const float4*)(aggrow + c0);
      const float4 d = *(const float4*)(aggrow + c0 + 4);
      tmp[0] = a.x; tmp[1] = a.y; tmp[2] = a.z; tmp[3] = a.w;
      tmp[4] = d.x; tmp[5] = d.y; tmp[6] = d.z; tmp[7] = d.w;
    }
#pragma unroll
    for (int j = 0; j < 8; ++j) bfa[0][j] = (bf16_t)tmp[j];
#pragma unroll
    for (int kc = 1; kc < 4; ++kc) {
      const int c0 = kc * 32 + quad * 8 - 4;
      const float4 a = *(const float4*)(aggrow + c0);
      const float4 d = *(const float4*)(aggrow + c0 + 4);
      tmp[0] = a.x; tmp[1] = a.y; tmp[2] = a.z; tmp[3] = a.w;
      tmp[4] = d.x; tmp[5] = d.y; tmp[6] = d.z; tmp[7] = d.w;
#pragma unroll
      for (int j = 0; j < 8; ++j) bfa[kc][j] = (bf16_t)tmp[j];
    }
    if (quad == 0) {
      const float4 a = *(const float4*)(aggrow + 124);
      tmp[0] = a.x; tmp[1] = a.y; tmp[2] = a.z; tmp[3] = a.w;
      tmp[4] = 0.f; tmp[5] = 0.f; tmp[6] = 0.f; tmp[7] = 0.f;
#pragma unroll
      for (int j = 0; j < 8; ++j) bfa[4][j] = (bf16_t)tmp[j];
    } else bfa[4] = bzero8();
  }

  // ---- layer 1 (swapped), weights at use: h1[row][n] ----
#pragma unroll
  for (int ct = 0; ct < 8; ++ct) {
    const int nb = ct * 16 + quad * 4;
    f32x4 acc = make4(s.b1f[nb], s.b1f[nb + 1], s.b1f[nb + 2], s.b1f[nb + 3]);
#pragma unroll
    for (int kc = 0; kc < 5; ++kc) {
      const bf16x8 w = *(const bf16x8*)&ow1f_g[(((ct * 5 + kc) * 4 + quad) * 16 + lm) * 8];
      acc = __builtin_amdgcn_mfma_f32_16x16x32_bf16(w, bfa[kc], acc, 0, 0, 0);
    }
    pack_store4(&s.h1[row * 136 + ct * 16 + quad * 4], acc);
  }
  // no barrier: h1 rows are wave-private

  bf16x8 af[4];
#pragma unroll
  for (int kc = 0; kc < 4; ++kc)
    af[kc] = *(const bf16x8*)&s.h1[row * 136 + kc * 32 + quad * 8];

  // ---- layer 2 (swapped), weights at use: h2[row][m] ----
#pragma unroll
  for (int ct = 0; ct < 8; ++ct) {
    const int mb = ct * 16 + quad * 4;
    f32x4 acc = make4(s.b2f[mb], s.b2f[mb + 1], s.b2f[mb + 2], s.b2f[mb + 3]);
#pragma unroll
    for (int kc = 0; kc < 4; ++kc) {
      const bf16x8 w = *(const bf16x8*)&ow2f_g[(((ct * 4 + kc) * 4 + quad) * 16 + lm) * 8];
      acc = __builtin_amdgcn_mfma_f32_16x16x32_bf16(w, af[kc], acc, 0, 0, 0);
    }
    pack_store4(&s.h2[row * 136 + ct * 16 + quad * 4], acc);
  }
  // no barrier: layer-3 lanes read their own wave's rows

  // ---- layer 3 (VALU) + residual + store ----
  {
    const int rloc = tid >> 2;
    const int d    = tid & 3;
    float a3 = s.b3f[d];
#pragma unroll
    for (int g = 0; g < 16; ++g) {
      const bf16x8 hv = *(const bf16x8*)&s.h2[rloc * 136 + g * 8];
#pragma unroll
      for (int j = 0; j < 8; ++j)
        a3 += (float)hv[j] * s.w3f[(g * 8 + j) * 4 + d];
    }
    a3 += (float)s.xres[rloc * 4 + d];
    const int r  = r0 + rloc;
    const int n  = r % NN;
    const int bt = r / NN;
    const int t  = bt % NT;
    const int b  = bt / NT;
    if (t < NT - 1) {
      const int oidx = ((b * NN + n) * (NT - 1) + t) * ND + d;
      if (isbf) ((bf16_t*)outp)[oidx] = (bf16_t)a3;
      else      ((float*)outp)[oidx]  = a3;
    }
  }
}

extern "C" void kernel_launch(void* const* d_in, const int* in_sizes, int n_in,
                              void* d_out, int out_size, void* d_ws, size_t ws_size,
                              hipStream_t stream) {
  // d_in[2] rel_rec, d_in[3] rel_send: fixed one-hot structure, computed
  // analytically. d_in[14] pred_steps == 1.
  char* ws = (char*)d_ws;
  bf16_t* cb = (bf16_t*)(ws + 16);             // canonical bf16 arrays + fragments
  float* aggbuf = (float*)(ws + AGG_BYTE_OFF); // 24000*128*4 B = 12.29 MB

  convert_kernel<<<dim3(256), dim3(256), 0, stream>>>(
      d_in[0], d_in[1], d_in[4], d_in[5], d_in[6], d_in[7],
      d_in[8], d_in[9], d_in[10], d_in[11], d_in[12], d_in[13], d_ws);

  edge_kernel<<<dim3(NB * NT * 2), dim3(256), 0, stream>>>(
      cb + C_INPUTS, cb + C_RELTYPE, cb + C_W1F, cb + C_W2F,
      cb + C_B2, aggbuf);

  node_kernel<<<dim3((NB * NT * NN) / 64), dim3(256), 0, stream>>>(
      cb + C_INPUTS, cb + C_OW1F, cb + C_OB1, cb + C_OW2F, cb + C_OB2,
      cb + C_OW3, cb + C_OB3, (const int*)d_ws, aggbuf, d_out);
}